// Round 1
// baseline (377.801 us; speedup 1.0000x reference)
//
#include <hip/hip_runtime.h>

// MQCCLayer forward on MI355X.
// Key identity: conv(x/mag, w) * mag == conv(x, w)  (conv linear in x),
// so the per-sample L2 normalization cancels. OUT_CHANNELS == C*F, so the
// slice is a no-op. Remaining work: depthwise 3x3 same-pad conv with F=2
// shared unit-norm filters. out[b, c*2+f, h, w] = sum_{kh,kw} x[b,c,h-1+kh,w-1+kw]*wf[f,kh,kw]
// (jax.lax conv is cross-correlation: no kernel flip).

#define BATCH 32
#define CIN   4
#define HH    512
#define WW    512
#define NF    2
#define W4    (WW / 4)   // 128 float4-quads per row

__global__ __launch_bounds__(256) void mqcc_kernel(
    const float* __restrict__ x,
    const float* __restrict__ angles,
    float* __restrict__ out)
{
    // --- normalized filters (uniform across all threads -> scalar loads/ops) ---
    float wf[NF][9];
#pragma unroll
    for (int f = 0; f < NF; ++f) {
        float s = 0.f;
#pragma unroll
        for (int k = 0; k < 9; ++k) {
            float a = angles[f * 9 + k];
            s += a * a;
        }
        float inv = rsqrtf(s);
#pragma unroll
        for (int k = 0; k < 9; ++k) wf[f][k] = angles[f * 9 + k] * inv;
    }

    // tid -> (b, c, h, w4); all power-of-2 fields.
    // bits: w4 = [0..6], h = [7..15], c = [16..17], b = [18..22]
    int tid = blockIdx.x * 256 + threadIdx.x;
    int w4 = tid & (W4 - 1);
    int h  = (tid >> 7) & (HH - 1);
    int c  = (tid >> 16) & (CIN - 1);
    int b  = tid >> 18;

    int w0 = w4 << 2;
    const float* xp = x + ((size_t)(b * CIN + c) * HH) * WW;

    // 3 input rows x 6 cols (w0-1 .. w0+4), zero-padded.
    float in[3][6];
#pragma unroll
    for (int r = 0; r < 3; ++r) {
        int hr = h + r - 1;
        if (hr >= 0 && hr < HH) {            // wave-uniform branch (h uniform per wave)
            const float* row = xp + (size_t)hr * WW;
            float4 v = *(const float4*)(row + w0);
            in[r][1] = v.x; in[r][2] = v.y; in[r][3] = v.z; in[r][4] = v.w;
            // clamped in-bounds loads + select (no OOB, no divergent load)
            float lft = row[(w4 > 0) ? (w0 - 1) : 0];
            float rgt = row[(w4 < W4 - 1) ? (w0 + 4) : (WW - 1)];
            in[r][0] = (w4 > 0)       ? lft : 0.f;
            in[r][5] = (w4 < W4 - 1)  ? rgt : 0.f;
        } else {
#pragma unroll
            for (int k = 0; k < 6; ++k) in[r][k] = 0.f;
        }
    }

    // both filters share the input window (halves input traffic per output)
#pragma unroll
    for (int f = 0; f < NF; ++f) {
        float a0 = 0.f, a1 = 0.f, a2 = 0.f, a3 = 0.f;
#pragma unroll
        for (int r = 0; r < 3; ++r) {
#pragma unroll
            for (int k = 0; k < 3; ++k) {
                float wv = wf[f][r * 3 + k];
                a0 = fmaf(wv, in[r][k + 0], a0);
                a1 = fmaf(wv, in[r][k + 1], a1);
                a2 = fmaf(wv, in[r][k + 2], a2);
                a3 = fmaf(wv, in[r][k + 3], a3);
            }
        }
        float4 acc = make_float4(a0, a1, a2, a3);
        float* op = out + ((((size_t)b * (CIN * NF) + (c * NF + f)) * HH + h) * WW + w0);
        *(float4*)op = acc;
    }
}

extern "C" void kernel_launch(void* const* d_in, const int* in_sizes, int n_in,
                              void* d_out, int out_size, void* d_ws, size_t ws_size,
                              hipStream_t stream) {
    const float* x      = (const float*)d_in[0];
    const float* angles = (const float*)d_in[1];
    float* out          = (float*)d_out;

    // total quad-tasks: B*C*H*(W/4) = 32*4*512*128 = 2^23 threads
    const int total  = BATCH * CIN * HH * W4;
    const int block  = 256;
    const int grid   = total / block;   // 32768

    hipLaunchKernelGGL(mqcc_kernel, dim3(grid), dim3(block), 0, stream,
                       x, angles, out);
}

// Round 3
// 363.177 us; speedup vs baseline: 1.0403x; 1.0403x over previous
//
#include <hip/hip_runtime.h>

// MQCCLayer forward on MI355X.
// conv(x/mag, w) * mag == conv(x, w) (conv linear in x) -> sample L2 norm cancels.
// OUT_CHANNELS == C*F -> slice is a no-op. Remaining: depthwise 3x3 same-pad conv,
// F=2 shared unit-norm filters (cross-correlation, no flip).
// out[b, c*2+f, h, w] = sum_{kh,kw} x[b,c,h-1+kh,w-1+kw] * wf[f][kh][kw]
//
// Structure: thread = 4 output rows x 4 cols x 2 filters (32 outputs),
// rolling 6-row input window; edge cols via __shfl from neighbor lane
// (2 predicated 1-lane loads/row at wave boundary); bijective XCD swizzle;
// nontemporal output stores (out never re-read; keep x in L2/L3).

#define BATCH 32
#define CIN   4
#define HH    512
#define WW    512
#define NF    2
#define W4    (WW / 4)    // 128 col-quads per row
#define HG    (HH / 4)    // 128 row-groups per image
#define NXCD  8

// native vector type: __builtin_nontemporal_store requires it (HIP float4 is a class)
typedef float floatx4 __attribute__((ext_vector_type(4)));

__global__ __launch_bounds__(256) void mqcc_kernel(
    const float* __restrict__ x,
    const float* __restrict__ angles,
    float* __restrict__ out)
{
    // --- normalized filters (uniform -> scalar loads/ops) ---
    float wf[NF][9];
#pragma unroll
    for (int f = 0; f < NF; ++f) {
        float s = 0.f;
#pragma unroll
        for (int k = 0; k < 9; ++k) { float a = angles[f * 9 + k]; s += a * a; }
        float inv = rsqrtf(s);
#pragma unroll
        for (int k = 0; k < 9; ++k) wf[f][k] = angles[f * 9 + k] * inv;
    }

    // bijective XCD swizzle: grid = 8192 blocks, 8192 % 8 == 0, chunk = 1024.
    int bid  = blockIdx.x;
    int wid  = (bid & (NXCD - 1)) * (gridDim.x / NXCD) + (bid / NXCD);
    int tid  = wid * 256 + threadIdx.x;

    // bits: w4 [0..6], hgroup [7..13], c [14..15], b [16..20]
    int w4 = tid & (W4 - 1);
    int hg = (tid >> 7) & (HG - 1);
    int c  = (tid >> 14) & (CIN - 1);
    int b  = tid >> 16;

    int w0    = w4 << 2;
    int hbase = hg << 2;
    int lane  = threadIdx.x & 63;
    const float* xp = x + ((size_t)(b * CIN + c) * HH) * WW;

    float acc[4][NF][4];
#pragma unroll
    for (int j = 0; j < 4; ++j)
#pragma unroll
        for (int f = 0; f < NF; ++f)
#pragma unroll
            for (int q = 0; q < 4; ++q) acc[j][f][q] = 0.f;

    // rolling window over 6 input rows: ri = hbase-1 .. hbase+4
#pragma unroll
    for (int i = 0; i < 6; ++i) {
        int ri = hbase + i - 1;
        if (ri >= 0 && ri < HH) {          // wave-uniform (hg uniform per wave)
            const float* row = xp + (size_t)ri * WW;
            floatx4 v = *(const floatx4*)(row + w0);
            float l  = __shfl_up(v.w, 1, 64);
            float rt = __shfl_down(v.x, 1, 64);
            if (lane == 0)  l  = (w4 == 0)      ? 0.f : row[w0 - 1];
            if (lane == 63) rt = (w4 == W4 - 1) ? 0.f : row[w0 + 4];
            float e[6] = { l, v.x, v.y, v.z, v.w, rt };
            // input row ri feeds output row j = i - kh (within this group)
#pragma unroll
            for (int kh = 0; kh < 3; ++kh) {
                int j = i - kh;
                if (j >= 0 && j < 4) {
#pragma unroll
                    for (int f = 0; f < NF; ++f) {
                        float wv0 = wf[f][kh * 3 + 0];
                        float wv1 = wf[f][kh * 3 + 1];
                        float wv2 = wf[f][kh * 3 + 2];
#pragma unroll
                        for (int q = 0; q < 4; ++q) {
                            float s = acc[j][f][q];
                            s = fmaf(wv0, e[q + 0], s);
                            s = fmaf(wv1, e[q + 1], s);
                            s = fmaf(wv2, e[q + 2], s);
                            acc[j][f][q] = s;
                        }
                    }
                }
            }
        }
    }

    // epilogue: 8 nontemporal 16B stores (out is write-once, never re-read)
#pragma unroll
    for (int j = 0; j < 4; ++j) {
#pragma unroll
        for (int f = 0; f < NF; ++f) {
            floatx4 o = { acc[j][f][0], acc[j][f][1], acc[j][f][2], acc[j][f][3] };
            float* op = out + ((((size_t)b * (CIN * NF) + (c * NF + f)) * HH + (hbase + j)) * WW + w0);
            __builtin_nontemporal_store(o, (floatx4*)op);
        }
    }
}

extern "C" void kernel_launch(void* const* d_in, const int* in_sizes, int n_in,
                              void* d_out, int out_size, void* d_ws, size_t ws_size,
                              hipStream_t stream) {
    const float* x      = (const float*)d_in[0];
    const float* angles = (const float*)d_in[1];
    float* out          = (float*)d_out;

    // threads = B*C*HG*W4 = 32*4*128*128 = 2^21 -> 8192 blocks of 256
    const int total = BATCH * CIN * HG * W4;
    const int block = 256;
    const int grid  = total / block;   // 8192, divisible by 8 (XCD swizzle bijective)

    hipLaunchKernelGGL(mqcc_kernel, dim3(grid), dim3(block), 0, stream,
                       x, angles, out);
}